// Round 3
// baseline (223.278 us; speedup 1.0000x reference)
//
#include <hip/hip_runtime.h>

#define NODE 100
#define BATCH 64
#define DIM 128
#define IN_DIM 5
#define TOPK 30
#define INTER 256
#define NB (BATCH*NODE)   /* 6400 */
#define EPS 1e-5f
#define SLOPE 0.2f

#define LIN_BLOCKS 1600            /* 4 rows per block (wave per row) */
#define TOPK_BLOCKS 25             /* 4 rows per block */
#define ZERO_BLOCK (LIN_BLOCKS + TOPK_BLOCKS)
#define FRONT_GRID (ZERO_BLOCK + 1)

// stats accumulator layout (floats):
//   [0:128)   sum1   [128:256) sq1      (bn1, over agg)
//   [256:384) sum2   [384:512) sq2      (bn2, over x3)
//   [512:768) sum3   [768:1024) sq3     (bn3, over o1)

// ===== K1: fused front =====================================================
// blocks [0,1600): h = x@w_lin^T + attention row-scalars ai, aj (wave/row)
// blocks [1600,1625): cosine top-30 (wave/row, shuffle argmax, no barriers in loop)
// block 1625: zero the stats accumulators
__global__ __launch_bounds__(256) void k_front(
        const float* __restrict__ x, const float* __restrict__ emb,
        const float* __restrict__ w_lin,
        const float* __restrict__ att_i, const float* __restrict__ att_j,
        const float* __restrict__ att_em_i, const float* __restrict__ att_em_j,
        float* __restrict__ h, float* __restrict__ ai, float* __restrict__ aj,
        int* __restrict__ idx, float* __restrict__ stats) {
    int b = blockIdx.x;
    int t = threadIdx.x;
    int w = t >> 6;      // wave in block
    int l = t & 63;      // lane
    if (b < LIN_BLOCKS) {
        int row = b*4 + w;
        int node = row % NODE;
        float xv[IN_DIM];
#pragma unroll
        for (int c = 0; c < IN_DIM; ++c) xv[c] = x[row*IN_DIM + c];
        float h0 = 0.f, h1 = 0.f;
#pragma unroll
        for (int c = 0; c < IN_DIM; ++c) {
            h0 += xv[c] * w_lin[l*IN_DIM + c];
            h1 += xv[c] * w_lin[(l+64)*IN_DIM + c];
        }
        h[row*DIM + l]      = h0;
        h[row*DIM + l + 64] = h1;
        float e0 = emb[node*DIM + l], e1 = emb[node*DIM + l + 64];
        float si = h0*att_i[l] + e0*att_em_i[l] + h1*att_i[l+64] + e1*att_em_i[l+64];
        float sj = h0*att_j[l] + e0*att_em_j[l] + h1*att_j[l+64] + e1*att_em_j[l+64];
#pragma unroll
        for (int m = 32; m >= 1; m >>= 1) {
            si += __shfl_xor(si, m, 64);
            sj += __shfl_xor(sj, m, 64);
        }
        if (l == 0) { ai[row] = si; aj[row] = sj; }
    } else if (b < ZERO_BLOCK) {
        __shared__ float eis[4][DIM];
        int i = (b - LIN_BLOCKS)*4 + w;      // target row 0..99
        eis[w][l]      = emb[i*DIM + l];
        eis[w][l + 64] = emb[i*DIM + l + 64];
        __syncthreads();
        int j0 = l, j1 = 64 + l;
        bool v1ok = (j1 < NODE);
        float d0 = 0.f, d1 = 0.f, ni = 0.f, n0 = 0.f, n1 = 0.f;
        for (int dd = 0; dd < DIM; ++dd) {
            float e = eis[w][dd];
            ni += e*e;
            float a0 = emb[j0*DIM + dd];
            d0 += e*a0; n0 += a0*a0;
            if (v1ok) { float a1 = emb[j1*DIM + dd]; d1 += e*a1; n1 += a1*a1; }
        }
        float sni = sqrtf(ni);
        float c0 = d0 / (sni * sqrtf(n0));
        float c1 = v1ok ? d1 / (sni * sqrtf(n1)) : -INFINITY;
        for (int r = 0; r < TOPK; ++r) {
            float bv; int bi;
            if (c1 > c0) { bv = c1; bi = j1; } else { bv = c0; bi = j0; } // tie -> lower idx
#pragma unroll
            for (int m = 32; m >= 1; m >>= 1) {
                float ov = __shfl_xor(bv, m, 64);
                int   oi = __shfl_xor(bi, m, 64);
                if (ov > bv || (ov == bv && oi < bi)) { bv = ov; bi = oi; }
            }
            if (l == 0) idx[i*TOPK + r] = bi;
            if (bi == j0) c0 = -INFINITY;      // invalidate winner, matches lax.top_k order
            if (bi == j1) c1 = -INFINITY;
        }
    } else {
        // zero stats accumulators (1024 floats)
#pragma unroll
        for (int q = 0; q < 4; ++q) stats[t + q*256] = 0.f;
    }
}

// ===== K2: edge attention + softmax + gather (wave/target) + bn1 stats =====
__global__ __launch_bounds__(256) void k_attagg(
        const float* __restrict__ h, const float* __restrict__ ai,
        const float* __restrict__ aj, const int* __restrict__ idx,
        const float* __restrict__ g_bias, float* __restrict__ agg,
        float* __restrict__ stats) {
    __shared__ float sv[4][DIM], sq[4][DIM];
    int t = threadIdx.x, w = t >> 6, l = t & 63;
    int tgt = blockIdx.x*4 + w;
    int node = tgt % NODE;
    int base = tgt - node;
    float a = -INFINITY; int s = 0;
    if (l < TOPK) {
        s = base + idx[node*TOPK + l];
        float v = ai[tgt] + aj[s];
        a = (v > 0.f) ? v : SLOPE*v;           // leaky relu
    }
    float m = a;
#pragma unroll
    for (int mm = 32; mm >= 1; mm >>= 1) m = fmaxf(m, __shfl_xor(m, mm, 64));
    float e = (l < TOPK) ? expf(a - m) : 0.f;
    float sum = e;
#pragma unroll
    for (int mm = 32; mm >= 1; mm >>= 1) sum += __shfl_xor(sum, mm, 64);
    float wgt = e / (sum + 1e-16f);
    float acc0 = 0.f, acc1 = 0.f;
#pragma unroll 10
    for (int r = 0; r < TOPK; ++r) {
        float wr = __shfl(wgt, r, 64);
        int   sr = __shfl(s,   r, 64);
        acc0 += wr * h[sr*DIM + l];
        acc1 += wr * h[sr*DIM + l + 64];
    }
    float v0 = acc0 + g_bias[l];
    float v1 = acc1 + g_bias[l + 64];
    agg[tgt*DIM + l]      = v0;
    agg[tgt*DIM + l + 64] = v1;
    sv[w][l] = v0;      sv[w][l+64] = v1;
    sq[w][l] = v0*v0;   sq[w][l+64] = v1*v1;
    __syncthreads();
    if (t < DIM) {
        float s1 = sv[0][t] + sv[1][t] + sv[2][t] + sv[3][t];
        float s2 = sq[0][t] + sq[1][t] + sq[2][t] + sq[3][t];
        atomicAdd(&stats[t], s1);
        atomicAdd(&stats[DIM + t], s2);
    }
}

// ===== K3: x3 = relu(bn1(agg)) * emb (float4) + bn2 stats ==================
__global__ __launch_bounds__(256) void k_x3(
        const float* __restrict__ agg, const float* __restrict__ emb,
        const float* __restrict__ g1, const float* __restrict__ b1,
        float* __restrict__ stats, float* __restrict__ x3) {
    __shared__ float pv[8][DIM], pq[8][DIM];
    int t = threadIdx.x;
    int i4 = blockIdx.x*256 + t;         // float4 index, 0..204799
    int c4 = (i4 & 31) * 4;
    int row = i4 >> 5;
    int node = row % NODE;
    float4 av = ((const float4*)agg)[i4];
    float4 ev = *(const float4*)&emb[node*DIM + c4];
    const float inv = 1.f/(float)NB;
    float o[4];
#pragma unroll
    for (int q = 0; q < 4; ++q) {
        int c = c4 + q;
        float mu = stats[c] * inv;
        float var = stats[DIM + c]*inv - mu*mu;
        float rs = rsqrtf(var + EPS);
        float val = (((const float*)&av)[q] - mu)*rs*g1[c] + b1[c];
        val = fmaxf(val, 0.f);
        o[q] = val * ((const float*)&ev)[q];
    }
    ((float4*)x3)[i4] = make_float4(o[0], o[1], o[2], o[3]);
    int lr = t >> 5;                     // local row 0..7
    *(float4*)&pv[lr][c4] = make_float4(o[0], o[1], o[2], o[3]);
    *(float4*)&pq[lr][c4] = make_float4(o[0]*o[0], o[1]*o[1], o[2]*o[2], o[3]*o[3]);
    __syncthreads();
    if (t < DIM) {
        float s1 = 0.f, s2 = 0.f;
#pragma unroll
        for (int r = 0; r < 8; ++r) { s1 += pv[r][t]; s2 += pq[r][t]; }
        atomicAdd(&stats[2*DIM + t], s1);
        atomicAdd(&stats[3*DIM + t], s2);
    }
}

// ===== K4: o1 = relu(bn2(x3)) @ w1^T + b1 (+ bn3 stats in epilogue) ========
__global__ __launch_bounds__(256) void k_gemm1(
        const float* __restrict__ x3,
        const float* __restrict__ g2, const float* __restrict__ b2v,
        const float* __restrict__ w1, const float* __restrict__ b1v,
        float* __restrict__ stats, float* __restrict__ o1) {
    __shared__ float aT[32][36];
    __shared__ float wT[32][260];
    __shared__ float ps[4][INTER], ps2[4][INTER];
    int tid = threadIdx.x;
    int r0 = blockIdx.x * 32;
    int cg = tid & 63;
    int rg = tid >> 6;
    const float inv = 1.f/(float)NB;
    float acc[8][4];
#pragma unroll
    for (int a = 0; a < 8; ++a)
#pragma unroll
        for (int b = 0; b < 4; ++b) acc[a][b] = 0.f;

    int kk = tid & 31;
    for (int k0 = 0; k0 < DIM; k0 += 32) {
        int k = k0 + kk;
        float mu = stats[2*DIM + k] * inv;
        float var = stats[3*DIM + k]*inv - mu*mu;
        float rs = rsqrtf(var + EPS);
        float gg = g2[k], bb = b2v[k];
#pragma unroll
        for (int j = 0; j < 4; ++j) {
            int row = (tid >> 5) + j*8;
            float v = (x3[(r0+row)*DIM + k] - mu)*rs*gg + bb;
            aT[row][kk] = fmaxf(v, 0.f);
        }
#pragma unroll
        for (int j = 0; j < 32; ++j) {
            int i = tid + j*256;
            int kk2 = i & 31, c = i >> 5;
            wT[kk2][c] = w1[c*DIM + k0 + kk2];
        }
        __syncthreads();
#pragma unroll
        for (int q4 = 0; q4 < 8; ++q4) {
            float4 av[8], wv[4];
#pragma unroll
            for (int rr = 0; rr < 8; ++rr)
                av[rr] = *(const float4*)&aT[rg*8+rr][q4*4];
#pragma unroll
            for (int q = 0; q < 4; ++q)
                wv[q] = *(const float4*)&wT[q4*4+q][cg*4];
#pragma unroll
            for (int rr = 0; rr < 8; ++rr) {
                acc[rr][0] += av[rr].x*wv[0].x + av[rr].y*wv[1].x + av[rr].z*wv[2].x + av[rr].w*wv[3].x;
                acc[rr][1] += av[rr].x*wv[0].y + av[rr].y*wv[1].y + av[rr].z*wv[2].y + av[rr].w*wv[3].y;
                acc[rr][2] += av[rr].x*wv[0].z + av[rr].y*wv[1].z + av[rr].z*wv[2].z + av[rr].w*wv[3].z;
                acc[rr][3] += av[rr].x*wv[0].w + av[rr].y*wv[1].w + av[rr].z*wv[2].w + av[rr].w*wv[3].w;
            }
        }
        __syncthreads();
    }
    int cbase = cg*4;
    float4 bv = *(const float4*)&b1v[cbase];
    float lv[4]  = {0.f, 0.f, 0.f, 0.f};
    float lv2[4] = {0.f, 0.f, 0.f, 0.f};
#pragma unroll
    for (int rr = 0; rr < 8; ++rr) {
        int row = r0 + rg*8 + rr;
        float o0 = acc[rr][0] + bv.x;
        float o1v = acc[rr][1] + bv.y;
        float o2 = acc[rr][2] + bv.z;
        float o3 = acc[rr][3] + bv.w;
        *(float4*)&o1[row*INTER + cbase] = make_float4(o0, o1v, o2, o3);
        lv[0] += o0;  lv2[0] += o0*o0;
        lv[1] += o1v; lv2[1] += o1v*o1v;
        lv[2] += o2;  lv2[2] += o2*o2;
        lv[3] += o3;  lv2[3] += o3*o3;
    }
    *(float4*)&ps[rg][cbase]  = make_float4(lv[0], lv[1], lv[2], lv[3]);
    *(float4*)&ps2[rg][cbase] = make_float4(lv2[0], lv2[1], lv2[2], lv2[3]);
    __syncthreads();
    if (tid < INTER) {
        float s1 = ps[0][tid] + ps[1][tid] + ps[2][tid] + ps[3][tid];
        float s2 = ps2[0][tid] + ps2[1][tid] + ps2[2][tid] + ps2[3][tid];
        atomicAdd(&stats[4*DIM + tid], s1);
        atomicAdd(&stats[4*DIM + INTER + tid], s2);
    }
}

// ===== K5: out = relu(bn3(o1)) @ w2^T + b2 (wave/row, shuffle reduce) ======
__global__ __launch_bounds__(256) void k_out(
        const float* __restrict__ o1, const float* __restrict__ stats,
        const float* __restrict__ g3, const float* __restrict__ b3,
        const float* __restrict__ w2, const float* __restrict__ b2s,
        float* __restrict__ out) {
    int t = threadIdx.x, w = t >> 6, l = t & 63;
    int row = blockIdx.x*4 + w;
    const float inv = 1.f/(float)NB;
    float4 v = *(const float4*)&o1[row*INTER + l*4];
    float s = 0.f;
#pragma unroll
    for (int q = 0; q < 4; ++q) {
        int c = l*4 + q;
        float mu = stats[4*DIM + c]*inv;
        float var = stats[4*DIM + INTER + c]*inv - mu*mu;
        float rs = rsqrtf(var + EPS);
        float val = (((const float*)&v)[q] - mu)*rs*g3[c] + b3[c];
        val = fmaxf(val, 0.f);
        s += val * w2[c];
    }
#pragma unroll
    for (int m = 32; m >= 1; m >>= 1) s += __shfl_xor(s, m, 64);
    if (l == 0) out[row] = s + b2s[0];
}

extern "C" void kernel_launch(void* const* d_in, const int* in_sizes, int n_in,
                              void* d_out, int out_size, void* d_ws, size_t ws_size,
                              hipStream_t stream) {
    const float* x        = (const float*)d_in[0];
    const float* emb      = (const float*)d_in[1];
    const float* w_lin    = (const float*)d_in[2];
    const float* att_i    = (const float*)d_in[3];
    const float* att_j    = (const float*)d_in[4];
    const float* att_em_i = (const float*)d_in[5];
    const float* att_em_j = (const float*)d_in[6];
    const float* g_bias   = (const float*)d_in[7];
    const float* bn1_g    = (const float*)d_in[8];
    const float* bn1_b    = (const float*)d_in[9];
    const float* bn2_g    = (const float*)d_in[10];
    const float* bn2_b    = (const float*)d_in[11];
    const float* bn3_g    = (const float*)d_in[12];
    const float* bn3_b    = (const float*)d_in[13];
    const float* w1       = (const float*)d_in[14];
    const float* b1       = (const float*)d_in[15];
    const float* w2       = (const float*)d_in[16];
    const float* b2       = (const float*)d_in[17];
    float* out = (float*)d_out;

    float* ws    = (float*)d_ws;
    float* h     = ws;                 // 819200
    float* agg   = ws + 819200;        // 819200
    float* x3    = ws + 1638400;       // 819200
    float* o1    = ws + 2457600;       // 1638400
    float* ai    = ws + 4096000;       // 6400
    float* aj    = ws + 4102400;       // 6400
    float* stats = ws + 4108800;       // 1024
    int*   idx   = (int*)(ws + 4110000); // 3000 ints

    k_front<<<FRONT_GRID, 256, 0, stream>>>(x, emb, w_lin, att_i, att_j,
                                            att_em_i, att_em_j, h, ai, aj, idx, stats);
    k_attagg<<<NB/4, 256, 0, stream>>>(h, ai, aj, idx, g_bias, agg, stats);
    k_x3<<<NB*DIM/4/256, 256, 0, stream>>>(agg, emb, bn1_g, bn1_b, stats, x3);
    k_gemm1<<<NB/32, 256, 0, stream>>>(x3, bn2_g, bn2_b, w1, b1, stats, o1);
    k_out<<<NB/4, 256, 0, stream>>>(o1, stats, bn3_g, bn3_b, w2, b2, out);
}

// Round 5
// 165.766 us; speedup vs baseline: 1.3469x; 1.3469x over previous
//
#include <hip/hip_runtime.h>

#define NODE 100
#define BATCH 64
#define DIM 128
#define IN_DIM 5
#define TOPK 30
#define INTER 256
#define NB (BATCH*NODE)   /* 6400 */
#define EPS 1e-5f
#define SLOPE 0.2f
#define REP 32            /* stat replicas to kill same-line atomic contention */

// scratch float offsets
#define OFF_AGG    0
#define OFF_X3     819200
#define OFF_O1     1638400
#define OFF_U      3276800   /* u_i[0..4], u_j[5..9] */
#define OFF_EI     3276816   /* 100 (pad 112) */
#define OFF_EJ     3276928   /* 100 (pad 112) */
#define OFF_STATA  3277056   /* REP*32  = 1024:  [rep*32 + 0..4]=S, [5..19]=M(ut) */
#define OFF_STAT2  3278080   /* REP*256 = 8192:  [rep*256 + 0..127]=sum, [128..255]=sq */
#define OFF_STAT3  3286272   /* REP*512 = 16384: [rep*512 + 0..255]=sum, [256..511]=sq */
#define ZERO_LEN   25600     /* statA..stat3 contiguous */
#define OFF_IDX    3302656   /* 3000 ints */

// ===== K1: topk (blocks 0..24) + setup scalars (25) + zero stats (26) ======
__global__ __launch_bounds__(256) void k_front(
        const float* __restrict__ emb, const float* __restrict__ w_lin,
        const float* __restrict__ att_i, const float* __restrict__ att_j,
        const float* __restrict__ att_em_i, const float* __restrict__ att_em_j,
        float* __restrict__ ws, int* __restrict__ idx) {
    __shared__ float smem[12800 + 128];
    int b = blockIdx.x, t = threadIdx.x, w = t >> 6, l = t & 63;
    if (b < 25) {
        // ---- cosine top-30, fully LDS-resident transposed emb ----
        float* eT = smem;            // [128][100] : eT[d*100 + node]
        float* nsq = smem + 12800;   // [100]
        for (int i = t; i < NODE*DIM; i += 256) {
            int node = i >> 7, d = i & 127;
            eT[d*NODE + node] = emb[i];
        }
        __syncthreads();
        if (t < NODE) {
            float s = 0.f;
            for (int d = 0; d < DIM; ++d) { float v = eT[d*NODE + t]; s += v*v; }
            nsq[t] = s;
        }
        __syncthreads();
        int i = b*4 + w;             // target row
        int j0 = l, j1 = l + 64;
        bool ok1 = (j1 < NODE);
        float d0 = 0.f, d1 = 0.f;
        for (int dd = 0; dd < DIM; ++dd) {
            float ei = eT[dd*NODE + i];               // broadcast
            d0 += ei * eT[dd*NODE + j0];              // lane-contig
            if (ok1) d1 += ei * eT[dd*NODE + j1];
        }
        float sni = sqrtf(nsq[i]);
        float c0 = d0 / (sni * sqrtf(nsq[j0]));
        float c1 = ok1 ? d1 / (sni * sqrtf(nsq[j1])) : -INFINITY;
        for (int r = 0; r < TOPK; ++r) {
            float bv; int bi;
            if (c1 > c0) { bv = c1; bi = j1; } else { bv = c0; bi = j0; }
#pragma unroll
            for (int m = 32; m >= 1; m >>= 1) {
                float ov = __shfl_xor(bv, m, 64);
                int   oi = __shfl_xor(bi, m, 64);
                if (ov > bv || (ov == bv && oi < bi)) { bv = ov; bi = oi; }
            }
            if (l == 0) idx[i*TOPK + r] = bi;
            if (bi == j0) c0 = -INFINITY;
            if (bi == j1) c1 = -INFINITY;
        }
    } else if (b == 25) {
        // ---- u_i = w_lin^T att_i, u_j likewise; e_i/e_j per node ----
        float* Pi = smem;            // [5][128]
        float* Pj = smem + 640;      // [5][128]
        if (t < DIM) {
            float wi = att_i[t], wj = att_j[t];
#pragma unroll
            for (int c = 0; c < IN_DIM; ++c) {
                float wl = w_lin[t*IN_DIM + c];
                Pi[c*128 + t] = wl*wi;
                Pj[c*128 + t] = wl*wj;
            }
        }
        __syncthreads();
        if (t < 10) {
            int c = (t < 5) ? t : t - 5;
            const float* P = (t < 5) ? Pi : Pj;
            float s = 0.f;
            for (int k = 0; k < DIM; ++k) s += P[c*128 + k];
            ws[OFF_U + t] = s;
        }
        float a0 = att_em_i[l], a1 = att_em_i[l+64];
        float b0 = att_em_j[l], b1 = att_em_j[l+64];
        for (int n = w*25; n < w*25 + 25; ++n) {
            float v0 = emb[n*DIM + l], v1 = emb[n*DIM + l + 64];
            float pi = v0*a0 + v1*a1;
            float pj = v0*b0 + v1*b1;
#pragma unroll
            for (int m = 32; m >= 1; m >>= 1) {
                pi += __shfl_xor(pi, m, 64);
                pj += __shfl_xor(pj, m, 64);
            }
            if (l == 0) { ws[OFF_EI + n] = pi; ws[OFF_EJ + n] = pj; }
        }
    } else {
        for (int i = t; i < ZERO_LEN; i += 256) ws[OFF_STATA + i] = 0.f;
    }
}

// ===== K2: attention agg in 5-dim space + 5->128 projection + bn1 sums =====
// 1600 blocks x 128 threads; block = 4 targets of one batch (2 waves x 2)
__global__ __launch_bounds__(128) void k_agg(
        const float* __restrict__ x, const float* __restrict__ w_lin,
        const float* __restrict__ g_bias, const int* __restrict__ idx,
        float* __restrict__ ws) {
    __shared__ float xl[NODE*IN_DIM];     // batch x rows (500)
    __shared__ float sjl[NODE];
    __shared__ float ul[10];
    __shared__ int   idl[4*TOPK];
    __shared__ float psum[2][20];
    int g = blockIdx.x, t = threadIdx.x, w = t >> 6, l = t & 63;
    int batch = g / 25;
    int nb0 = (g % 25) * 4;
    float* agg = ws + OFF_AGG;
    for (int i = t; i < NODE*IN_DIM; i += 128) xl[i] = x[batch*NODE*IN_DIM + i];
    for (int i = t; i < 4*TOPK; i += 128) idl[i] = idx[nb0*TOPK + i];
    if (t < 10) ul[t] = ws[OFF_U + t];
    __syncthreads();
    if (t < NODE) {
        float s = ws[OFF_EJ + t];
#pragma unroll
        for (int c = 0; c < IN_DIM; ++c) s += xl[t*IN_DIM + c] * ul[5 + c];
        sjl[t] = s;
    }
    __syncthreads();
    // per-lane output rows of w_lin
    float wl0[IN_DIM], wl1[IN_DIM];
#pragma unroll
    for (int c = 0; c < IN_DIM; ++c) {
        wl0[c] = w_lin[l*IN_DIM + c];
        wl1[c] = w_lin[(l+64)*IN_DIM + c];
    }
    float gb0 = g_bias[l], gb1 = g_bias[l+64];
    float S0=0,S1=0,S2=0,S3=0,S4=0;
    float M[15];
#pragma unroll
    for (int m = 0; m < 15; ++m) M[m] = 0.f;
    for (int lt = w; lt < 4; lt += 2) {
        int node = nb0 + lt;
        int tgt = batch*NODE + node;
        float si = ws[OFF_EI + node];
#pragma unroll
        for (int c = 0; c < IN_DIM; ++c) si += xl[node*IN_DIM + c] * ul[c];
        // pass 1: max
        float mx = -INFINITY;
#pragma unroll
        for (int r = 0; r < TOPK; ++r) {
            int s = idl[lt*TOPK + r];
            float a = si + sjl[s];
            a = (a > 0.f) ? a : SLOPE*a;
            mx = fmaxf(mx, a);
        }
        // pass 2: exp-sum + 5-dim weighted x accumulation (unnormalized)
        float ssum = 0.f, x0=0,x1=0,x2=0,x3v=0,x4=0;
#pragma unroll
        for (int r = 0; r < TOPK; ++r) {
            int s = idl[lt*TOPK + r];
            float a = si + sjl[s];
            a = (a > 0.f) ? a : SLOPE*a;
            float e = expf(a - mx);
            ssum += e;
            const float* xr = &xl[s*IN_DIM];
            x0 += e*xr[0]; x1 += e*xr[1]; x2 += e*xr[2]; x3v += e*xr[3]; x4 += e*xr[4];
        }
        float inv = 1.f/(ssum + 1e-16f);
        float y0=x0*inv, y1=x1*inv, y2=x2*inv, y3=x3v*inv, y4=x4*inv;
        float o0 = y0*wl0[0]+y1*wl0[1]+y2*wl0[2]+y3*wl0[3]+y4*wl0[4] + gb0;
        float o1 = y0*wl1[0]+y1*wl1[1]+y2*wl1[2]+y3*wl1[3]+y4*wl1[4] + gb1;
        agg[tgt*DIM + l]      = o0;
        agg[tgt*DIM + l + 64] = o1;
        S0+=y0; S1+=y1; S2+=y2; S3+=y3; S4+=y4;
        M[0]+=y0*y0; M[1]+=y0*y1; M[2]+=y0*y2; M[3]+=y0*y3; M[4]+=y0*y4;
        M[5]+=y1*y1; M[6]+=y1*y2; M[7]+=y1*y3; M[8]+=y1*y4;
        M[9]+=y2*y2; M[10]+=y2*y3; M[11]+=y2*y4;
        M[12]+=y3*y3; M[13]+=y3*y4; M[14]+=y4*y4;
    }
    if (l == 0) {
        psum[w][0]=S0; psum[w][1]=S1; psum[w][2]=S2; psum[w][3]=S3; psum[w][4]=S4;
#pragma unroll
        for (int m = 0; m < 15; ++m) psum[w][5+m] = M[m];
    }
    __syncthreads();
    if (t < 20) {
        float p = psum[0][t] + psum[1][t];
        atomicAdd(&ws[OFF_STATA + (g & (REP-1))*32 + t], p);
    }
}

// ===== K3: x3 = relu(bn1(agg)) * emb  + bn2 partial sums ===================
__global__ __launch_bounds__(256) void k_x3(
        const float* __restrict__ w_lin, const float* __restrict__ g_bias,
        const float* __restrict__ emb,
        const float* __restrict__ g1, const float* __restrict__ b1,
        float* __restrict__ ws) {
    __shared__ float A[20];
    __shared__ float pv[8][DIM], pq[8][DIM];
    int t = threadIdx.x;
    if (t < 20) {
        float s = 0.f;
#pragma unroll
        for (int r = 0; r < REP; ++r) s += ws[OFF_STATA + r*32 + t];
        A[t] = s;
    }
    __syncthreads();
    const float invn = 1.f/(float)NB;
    int i4 = blockIdx.x*256 + t;
    int c4 = (i4 & 31) * 4;
    int row = i4 >> 5;
    int node = row % NODE;
    const float* agg = ws + OFF_AGG;
    float4 av = ((const float4*)agg)[i4];
    float4 ev = *(const float4*)&emb[node*DIM + c4];
    float o[4];
#pragma unroll
    for (int q = 0; q < 4; ++q) {
        int c = c4 + q;
        float w0 = w_lin[c*IN_DIM+0], w1 = w_lin[c*IN_DIM+1], w2 = w_lin[c*IN_DIM+2],
              w3 = w_lin[c*IN_DIM+3], w4 = w_lin[c*IN_DIM+4];
        float Sv = A[0]*w0 + A[1]*w1 + A[2]*w2 + A[3]*w3 + A[4]*w4;
        float Q  = w0*w0*A[5] + w1*w1*A[10] + w2*w2*A[14] + w3*w3*A[17] + w4*w4*A[19]
                 + 2.f*(w0*w1*A[6] + w0*w2*A[7] + w0*w3*A[8] + w0*w4*A[9]
                      + w1*w2*A[11] + w1*w3*A[12] + w1*w4*A[13]
                      + w2*w3*A[15] + w2*w4*A[16] + w3*w4*A[18]);
        float mv = Sv*invn;
        float mu = mv + g_bias[c];
        float var = fmaxf(Q*invn - mv*mv, 0.f);
        float rs = rsqrtf(var + EPS);
        float val = (((const float*)&av)[q] - mu)*rs*g1[c] + b1[c];
        val = fmaxf(val, 0.f);
        o[q] = val * ((const float*)&ev)[q];
    }
    ((float4*)(ws + OFF_X3))[i4] = make_float4(o[0], o[1], o[2], o[3]);
    int lr = t >> 5;
    *(float4*)&pv[lr][c4] = make_float4(o[0], o[1], o[2], o[3]);
    *(float4*)&pq[lr][c4] = make_float4(o[0]*o[0], o[1]*o[1], o[2]*o[2], o[3]*o[3]);
    __syncthreads();
    if (t < DIM) {
        float s1 = 0.f, s2 = 0.f;
#pragma unroll
        for (int r = 0; r < 8; ++r) { s1 += pv[r][t]; s2 += pq[r][t]; }
        int rep = blockIdx.x & (REP-1);
        atomicAdd(&ws[OFF_STAT2 + rep*256 + t], s1);
        atomicAdd(&ws[OFF_STAT2 + rep*256 + DIM + t], s2);
    }
}

// ===== K4: o1 = relu(bn2(x3)) @ w1^T + b1  (+ bn3 partials) ================
__global__ __launch_bounds__(256) void k_gemm1(
        const float* __restrict__ g2, const float* __restrict__ b2v,
        const float* __restrict__ w1, const float* __restrict__ b1v,
        float* __restrict__ ws) {
    __shared__ float aT[32][36];
    __shared__ float wT[32][260];
    __shared__ float ps[4][INTER], ps2[4][INTER];
    __shared__ float bn2raw[256], mu2l[DIM], rs2l[DIM];
    int tid = threadIdx.x;
    const float invn = 1.f/(float)NB;
    {
        float s = 0.f;
#pragma unroll
        for (int r = 0; r < REP; ++r) s += ws[OFF_STAT2 + r*256 + tid];
        bn2raw[tid] = s;
    }
    __syncthreads();
    if (tid < DIM) {
        float mu = bn2raw[tid]*invn;
        float var = fmaxf(bn2raw[DIM + tid]*invn - mu*mu, 0.f);
        mu2l[tid] = mu;
        rs2l[tid] = rsqrtf(var + EPS);
    }
    __syncthreads();
    const float* x3 = ws + OFF_X3;
    float* o1 = ws + OFF_O1;
    int r0 = blockIdx.x * 32;
    int cg = tid & 63;
    int rg = tid >> 6;
    float acc[8][4];
#pragma unroll
    for (int a = 0; a < 8; ++a)
#pragma unroll
        for (int b = 0; b < 4; ++b) acc[a][b] = 0.f;
    int kk = tid & 31;
    for (int k0 = 0; k0 < DIM; k0 += 32) {
        int k = k0 + kk;
        float mu = mu2l[k], rs = rs2l[k], gg = g2[k], bb = b2v[k];
#pragma unroll
        for (int j = 0; j < 4; ++j) {
            int row = (tid >> 5) + j*8;
            float v = (x3[(r0+row)*DIM + k] - mu)*rs*gg + bb;
            aT[row][kk] = fmaxf(v, 0.f);
        }
#pragma unroll
        for (int j = 0; j < 32; ++j) {
            int i = tid + j*256;
            int kk2 = i & 31, c = i >> 5;
            wT[kk2][c] = w1[c*DIM + k0 + kk2];
        }
        __syncthreads();
#pragma unroll
        for (int q4 = 0; q4 < 8; ++q4) {
            float4 av[8], wv[4];
#pragma unroll
            for (int rr = 0; rr < 8; ++rr)
                av[rr] = *(const float4*)&aT[rg*8+rr][q4*4];
#pragma unroll
            for (int q = 0; q < 4; ++q)
                wv[q] = *(const float4*)&wT[q4*4+q][cg*4];
#pragma unroll
            for (int rr = 0; rr < 8; ++rr) {
                acc[rr][0] += av[rr].x*wv[0].x + av[rr].y*wv[1].x + av[rr].z*wv[2].x + av[rr].w*wv[3].x;
                acc[rr][1] += av[rr].x*wv[0].y + av[rr].y*wv[1].y + av[rr].z*wv[2].y + av[rr].w*wv[3].y;
                acc[rr][2] += av[rr].x*wv[0].z + av[rr].y*wv[1].z + av[rr].z*wv[2].z + av[rr].w*wv[3].z;
                acc[rr][3] += av[rr].x*wv[0].w + av[rr].y*wv[1].w + av[rr].z*wv[2].w + av[rr].w*wv[3].w;
            }
        }
        __syncthreads();
    }
    int cbase = cg*4;
    float4 bv = *(const float4*)&b1v[cbase];
    float lv[4]  = {0.f,0.f,0.f,0.f};
    float lv2[4] = {0.f,0.f,0.f,0.f};
#pragma unroll
    for (int rr = 0; rr < 8; ++rr) {
        int row = r0 + rg*8 + rr;
        float o0 = acc[rr][0] + bv.x;
        float o1v = acc[rr][1] + bv.y;
        float o2 = acc[rr][2] + bv.z;
        float o3 = acc[rr][3] + bv.w;
        *(float4*)&o1[row*INTER + cbase] = make_float4(o0, o1v, o2, o3);
        lv[0]+=o0;  lv2[0]+=o0*o0;
        lv[1]+=o1v; lv2[1]+=o1v*o1v;
        lv[2]+=o2;  lv2[2]+=o2*o2;
        lv[3]+=o3;  lv2[3]+=o3*o3;
    }
    *(float4*)&ps[rg][cbase]  = make_float4(lv[0], lv[1], lv[2], lv[3]);
    *(float4*)&ps2[rg][cbase] = make_float4(lv2[0], lv2[1], lv2[2], lv2[3]);
    __syncthreads();
    if (tid < INTER) {
        float s1 = ps[0][tid] + ps[1][tid] + ps[2][tid] + ps[3][tid];
        float s2 = ps2[0][tid] + ps2[1][tid] + ps2[2][tid] + ps2[3][tid];
        int rep = blockIdx.x & (REP-1);
        atomicAdd(&ws[OFF_STAT3 + rep*512 + tid], s1);
        atomicAdd(&ws[OFF_STAT3 + rep*512 + INTER + tid], s2);
    }
}

// ===== K5: out = relu(bn3(o1)) @ w2^T + b2  (8 rows/block, wave/row) =======
__global__ __launch_bounds__(512) void k_out(
        const float* __restrict__ g3, const float* __restrict__ b3,
        const float* __restrict__ w2, const float* __restrict__ b2s,
        const float* __restrict__ ws, float* __restrict__ out) {
    __shared__ float raw[512], mu3l[INTER], rs3l[INTER];
    int t = threadIdx.x, w = t >> 6, l = t & 63;
    const float invn = 1.f/(float)NB;
    {
        float s = 0.f;
#pragma unroll
        for (int r = 0; r < REP; ++r) s += ws[OFF_STAT3 + r*512 + t];
        raw[t] = s;
    }
    __syncthreads();
    if (t < INTER) {
        float mu = raw[t]*invn;
        float var = fmaxf(raw[INTER + t]*invn - mu*mu, 0.f);
        mu3l[t] = mu;
        rs3l[t] = rsqrtf(var + EPS);
    }
    __syncthreads();
    int row = blockIdx.x*8 + w;
    const float* o1 = ws + OFF_O1;
    float4 v = *(const float4*)&o1[row*INTER + l*4];
    float s = 0.f;
#pragma unroll
    for (int q = 0; q < 4; ++q) {
        int c = l*4 + q;
        float val = (((const float*)&v)[q] - mu3l[c])*rs3l[c]*g3[c] + b3[c];
        val = fmaxf(val, 0.f);
        s += val * w2[c];
    }
#pragma unroll
    for (int m = 32; m >= 1; m >>= 1) s += __shfl_xor(s, m, 64);
    if (l == 0) out[row] = s + b2s[0];
}

extern "C" void kernel_launch(void* const* d_in, const int* in_sizes, int n_in,
                              void* d_out, int out_size, void* d_ws, size_t ws_size,
                              hipStream_t stream) {
    const float* x        = (const float*)d_in[0];
    const float* emb      = (const float*)d_in[1];
    const float* w_lin    = (const float*)d_in[2];
    const float* att_i    = (const float*)d_in[3];
    const float* att_j    = (const float*)d_in[4];
    const float* att_em_i = (const float*)d_in[5];
    const float* att_em_j = (const float*)d_in[6];
    const float* g_bias   = (const float*)d_in[7];
    const float* bn1_g    = (const float*)d_in[8];
    const float* bn1_b    = (const float*)d_in[9];
    const float* bn2_g    = (const float*)d_in[10];
    const float* bn2_b    = (const float*)d_in[11];
    const float* bn3_g    = (const float*)d_in[12];
    const float* bn3_b    = (const float*)d_in[13];
    const float* w1       = (const float*)d_in[14];
    const float* b1       = (const float*)d_in[15];
    const float* w2       = (const float*)d_in[16];
    const float* b2       = (const float*)d_in[17];
    float* out = (float*)d_out;
    float* ws  = (float*)d_ws;
    int*   idx = (int*)(ws + OFF_IDX);

    k_front<<<27, 256, 0, stream>>>(emb, w_lin, att_i, att_j, att_em_i, att_em_j, ws, idx);
    k_agg<<<1600, 128, 0, stream>>>(x, w_lin, g_bias, idx, ws);
    k_x3<<<NB*DIM/4/256, 256, 0, stream>>>(w_lin, g_bias, emb, bn1_g, bn1_b, ws);
    k_gemm1<<<NB/32, 256, 0, stream>>>(bn2_g, bn2_b, w1, b1, ws);
    k_out<<<NB/8, 512, 0, stream>>>(bn3_g, bn3_b, w2, b2, ws, out);
}